// Round 5
// baseline (331.974 us; speedup 1.0000x reference)
//
#include <hip/hip_runtime.h>
#include <hip/hip_bf16.h>

#define LSEQ   16384
#define BATCH  32
#define NBS    64              // B*2 sequences
#define CHUNK  448
#define NCHUNK 37              // ceil(16384/448)

// ---------------------------------------------------------------------------
// Fused 3-layer conv kernel (round-1/3/4 verified version, unchanged).
// ---------------------------------------------------------------------------

__device__ __forceinline__ void mac10x10(float acc[10], const float x[10],
                                         const float* __restrict__ wr) {
#pragma unroll
  for (int wi = 0; wi < 10; ++wi) {
    float xv = x[wi];
#pragma unroll
    for (int w = 0; w < 10; ++w) {
      acc[w] = fmaf(xv, wr[wi - w + 10], acc[w]);   // kw = wi-w+10 in [1,19]
    }
  }
}

template <int NPAIRS, int LREL0>
__device__ __forceinline__ void conv_stage(const float* __restrict__ bufIn,
                                           float* __restrict__ bufOut,
                                           const float* __restrict__ W, float bias,
                                           int base, int tid) {
  if (tid < NPAIRS) {
    float acc0[10], acc1[10];
#pragma unroll
    for (int w = 0; w < 10; ++w) { acc0[w] = bias; acc1[w] = bias; }
    float x[10];
    const float* src;

    // cp = 0 : input row rr = 2*tid (+0), contributes only to row0 (kh=0)
    src = bufIn + tid;
#pragma unroll
    for (int wi = 0; wi < 10; ++wi) x[wi] = src[wi * 512];
    mac10x10(acc0, x, W);

    for (int cp = 1; cp < 22; ++cp) {
      src = bufIn + (cp & 1) * 256 + tid + (cp >> 1);
#pragma unroll
      for (int wi = 0; wi < 10; ++wi) x[wi] = src[wi * 512];
      mac10x10(acc0, x, W + cp * 22);        // kh = cp   for row0
      mac10x10(acc1, x, W + (cp - 1) * 22);  // kh = cp-1 for row1
    }

    // cp = 22 : contributes only to row1 (kh=21)
    src = bufIn + tid + 11;
#pragma unroll
    for (int wi = 0; wi < 10; ++wi) x[wi] = src[wi * 512];
    mac10x10(acc1, x, W + 21 * 22);

    // relu + zero-mask rows outside [0, L)
    int g0 = base + 2 * tid + LREL0;
    bool v0 = (g0 >= 0) && (g0 < LSEQ);
    bool v1 = (g0 + 1 >= 0) && (g0 + 1 < LSEQ);
#pragma unroll
    for (int w = 0; w < 10; ++w) {
      bufOut[w * 512 + tid]       = v0 ? fmaxf(acc0[w], 0.0f) : 0.0f;
      bufOut[w * 512 + 256 + tid] = v1 ? fmaxf(acc1[w], 0.0f) : 0.0f;
    }
  }
}

__global__ __launch_bounds__(256) void conv_fused_kernel(
    const int* __restrict__ inputs, const float* __restrict__ emb,
    const float* __restrict__ w1, const float* __restrict__ b1,
    const float* __restrict__ w2, const float* __restrict__ b2,
    const float* __restrict__ w3, const float* __restrict__ b3,
    float* __restrict__ convout /* [NBS][10][LSEQ] */) {
  __shared__ float bufA[10 * 512];
  __shared__ float bufB[10 * 512];

  int blk = blockIdx.x;
  int bs = blk / NCHUNK;
  int chunk = blk - bs * NCHUNK;
  int base = chunk * CHUNK;
  int tid = threadIdx.x;

  // ---- gather: emb rows [base-30, base+482)  (512 rows = 256 pairs) ----
  const int* tokp = inputs + bs * LSEQ;
#pragma unroll
  for (int j = 0; j < 2; ++j) {
    int rr = 2 * tid + j;
    int glob = base - 30 + rr;
    float v[10];
    if (glob >= 0 && glob < LSEQ) {
      int tok = tokp[glob];
      const float2* er = reinterpret_cast<const float2*>(emb + tok * 10);
#pragma unroll
      for (int k = 0; k < 5; ++k) { float2 t = er[k]; v[2 * k] = t.x; v[2 * k + 1] = t.y; }
    } else {
#pragma unroll
      for (int wi = 0; wi < 10; ++wi) v[wi] = 0.0f;
    }
#pragma unroll
    for (int wi = 0; wi < 10; ++wi) bufA[wi * 512 + j * 256 + tid] = v[wi];
  }
  __syncthreads();

  // conv1: rows [-20, 470) relative to base   (245 pairs)
  conv_stage<245, -20>(bufA, bufB, w1, b1[0], base, tid);
  __syncthreads();
  // conv2: rows [-10, 460)                    (235 pairs)
  conv_stage<235, -10>(bufB, bufA, w2, b2[0], base, tid);
  __syncthreads();
  // conv3: rows [0, 448)                      (224 pairs)
  conv_stage<224, 0>(bufA, bufB, w3, b3[0], base, tid);
  __syncthreads();

  // ---- coalesced copy-out: [bs][w][l] channel-major ----
  float* gbase = convout + bs * 10 * LSEQ;
#pragma unroll
  for (int w = 0; w < 10; ++w) {
    for (int l = tid; l < CHUNK; l += 256) {
      int g = base + l;
      if (g < LSEQ) gbase[w * LSEQ + g] = bufB[w * 512 + (l & 1) * 256 + (l >> 1)];
    }
  }
}

// ---------------------------------------------------------------------------
// Top-50 (sorted descending) per (bs, d) channel via MSB-first radix select.
// Channel staged ONCE into LDS (interleaved vals[k*256+tid]: stride-1 across
// lanes -> 2 lanes/bank, conflict-free). All 4 radix passes + collection read
// LDS. Register pressure ~25 VGPR (round-4's v[64]-in-registers version is
// suspected to have spilled to scratch: ~210 MB scratch traffic ~= the
// unexplained 70us). Histogram updates stay wave-aggregated (8 ballots ->
// one atomicAdd(popcount) by the leader lane).
// ---------------------------------------------------------------------------
__global__ __launch_bounds__(256) void topk_kernel(const float* __restrict__ convout,
                                                   float* __restrict__ fbuf) {
  __shared__ unsigned int vals[64 * 256];   // 64 KB
  __shared__ unsigned int hist[256];
  __shared__ unsigned int sh_prefix, sh_remK, sh_candN;
  __shared__ unsigned int cand[64];

  int blk = blockIdx.x;
  int bs = blk / 10;
  int d = blk - bs * 10;
  int tid = threadIdx.x;
  int lane = tid & 63;
  const float4* src4 =
      reinterpret_cast<const float4*>(convout + (bs * 10 + d) * LSEQ);

  // ---- stage channel into LDS (post-relu: float bits = uint order) ----
#pragma unroll 4
  for (int k = 0; k < 16; ++k) {
    float4 t = src4[k * 256 + tid];
    vals[(4 * k + 0) * 256 + tid] = (t.x > 0.0f) ? __float_as_uint(t.x) : 0u;
    vals[(4 * k + 1) * 256 + tid] = (t.y > 0.0f) ? __float_as_uint(t.y) : 0u;
    vals[(4 * k + 2) * 256 + tid] = (t.z > 0.0f) ? __float_as_uint(t.z) : 0u;
    vals[(4 * k + 3) * 256 + tid] = (t.w > 0.0f) ? __float_as_uint(t.w) : 0u;
  }

  unsigned prefix = 0;
  unsigned remK = 50;
  __syncthreads();

  for (int pass = 0; pass < 4; ++pass) {
    int shift = 24 - pass * 8;
    hist[tid] = 0;
    __syncthreads();
    unsigned maskHi = (pass == 0) ? 0u : (0xFFFFFFFFu << (shift + 8));
#pragma unroll 4
    for (int k = 0; k < 64; ++k) {
      unsigned vv = vals[k * 256 + tid];
      bool m = ((vv & maskHi) == prefix);
      unsigned long long mmask = __ballot(m);
      if (mmask == 0ull) continue;          // whole wave: nothing in this bucket
      unsigned bin = (vv >> shift) & 255u;
      if (m) {
        unsigned long long same = mmask;
#pragma unroll
        for (int kb = 0; kb < 8; ++kb) {
          unsigned long long bk = __ballot((bin >> kb) & 1u);
          same &= ((bin >> kb) & 1u) ? bk : ~bk;
        }
        int leader = __ffsll((long long)same) - 1;
        if (lane == leader)
          atomicAdd(&hist[bin], (unsigned)__popcll(same));
      }
    }
    __syncthreads();
    if (tid == 0) {
      unsigned cum = 0;
      int b = 255;
      for (; b >= 0; --b) {
        unsigned h = hist[b];
        if (cum + h >= remK) break;
        cum += h;
      }
      sh_prefix = prefix | ((unsigned)b << shift);
      sh_remK = remK - cum;
    }
    __syncthreads();
    prefix = sh_prefix;
    remK = sh_remK;
    __syncthreads();   // hist reads done before re-zeroing next pass
  }

  // ---- collect strictly-greater values + remK copies of threshold ----
  if (tid == 0) sh_candN = 0;
  __syncthreads();
  unsigned T = prefix;
#pragma unroll 4
  for (int k = 0; k < 64; ++k) {
    unsigned vv = vals[k * 256 + tid];
    if (vv > T) {
      unsigned pos = atomicAdd(&sh_candN, 1u);
      if (pos < 64) cand[pos] = vv;
    }
  }
  __syncthreads();
  unsigned G = sh_candN;           // == 50 - remK by construction
  if (tid < remK) cand[G + tid] = T;
  __syncthreads();

  // rank-sort 50 candidates, descending
  if (tid < 50) {
    unsigned vv = cand[tid];
    int rank = 0;
    for (int j = 0; j < 50; ++j) {
      unsigned u = cand[j];
      rank += (u > vv) || (u == vv && j < tid);
    }
    fbuf[bs * 500 + rank * 10 + d] = __uint_as_float(vv);
  }
}

// ---------------------------------------------------------------------------
// Per-(batch, direction) MHA + sum over queries + final dense + softmax.
// ---------------------------------------------------------------------------
__global__ __launch_bounds__(256) void mha_kernel(
    const float* __restrict__ fbuf,
    const float* __restrict__ wq, const float* __restrict__ bq,
    const float* __restrict__ wk, const float* __restrict__ bk,
    const float* __restrict__ wv, const float* __restrict__ bv,
    const float* __restrict__ wo, const float* __restrict__ bo,
    const float* __restrict__ wf, const float* __restrict__ bf,
    float* __restrict__ out) {
  __shared__ float f[2][50][10];
  __shared__ float Qm[50][2][10];
  __shared__ float Km[50][2][10];
  __shared__ float Vm[50][2][10];
  __shared__ float A2[2][50][50];
  __shared__ float Abar[2][50];
  __shared__ float OS[2][10];
  __shared__ float rr[10];

  int blk = blockIdx.x, b = blk >> 1, dir = blk & 1;
  int qs = dir, ks = dir ^ 1;
  int tid = threadIdx.x;

  for (int i = tid; i < 1000; i += 256) (&f[0][0][0])[i] = fbuf[b * 1000 + i];
  __syncthreads();

  // projections: Q from f[qs], K/V from f[ks]
  for (int i = tid; i < 1000; i += 256) {
    int q = i / 20, rem = i - q * 20;
    int h = rem / 10, e = rem - h * 10;
    const float* fq = f[qs][q];
    const float* fk = f[ks][q];
    float aq = bq[h * 10 + e], ak = bk[h * 10 + e], av = bv[h * 10 + e];
#pragma unroll
    for (int dd = 0; dd < 10; ++dd) {
      int wIdx = dd * 20 + h * 10 + e;
      aq = fmaf(fq[dd], wq[wIdx], aq);
      ak = fmaf(fk[dd], wk[wIdx], ak);
      av = fmaf(fk[dd], wv[wIdx], av);
    }
    Qm[q][h][e] = aq; Km[q][h][e] = ak; Vm[q][h][e] = av;
  }
  __syncthreads();

  // softmax rows (h, q)
  for (int row = tid; row < 100; row += 256) {
    int h = row / 50, q = row - h * 50;
    const float* Qr = Qm[q][h];
    float lg[50], m = -1e30f;
#pragma unroll
    for (int s = 0; s < 50; ++s) {
      const float* Kr = Km[s][h];
      float t = 0.0f;
#pragma unroll
      for (int e = 0; e < 10; ++e) t = fmaf(Qr[e], Kr[e], t);
      t *= 0.31622776601683794f;   // 1/sqrt(10)
      lg[s] = t; m = fmaxf(m, t);
    }
    float sum = 0.0f;
#pragma unroll
    for (int s = 0; s < 50; ++s) { float p = __expf(lg[s] - m); lg[s] = p; sum += p; }
    float inv = 1.0f / sum;
#pragma unroll
    for (int s = 0; s < 50; ++s) A2[h][q][s] = lg[s] * inv;
  }
  __syncthreads();

  // Abar[h][s] = sum_q A[h][q][s]
  for (int i = tid; i < 100; i += 256) {
    int h = i / 50, s = i - h * 50;
    float t = 0.0f;
#pragma unroll
    for (int q = 0; q < 50; ++q) t += A2[h][q][s];
    Abar[h][s] = t;
  }
  __syncthreads();
  if (tid < 20) {
    int h = tid / 10, e = tid - h * 10;
    float t = 0.0f;
#pragma unroll
    for (int s = 0; s < 50; ++s) t += Abar[h][s] * Vm[s][h][e];
    OS[h][e] = t;
  }
  __syncthreads();
  if (tid < 10) {
    int dc = tid;
    float t = 50.0f * bo[dc];
#pragma unroll
    for (int h = 0; h < 2; ++h)
#pragma unroll
      for (int e = 0; e < 10; ++e) t = fmaf(OS[h][e], wo[h * 100 + e * 10 + dc], t);
    rr[dc] = t;
  }
  __syncthreads();
  if (tid == 0) {
    float l0 = bf[0], l1 = bf[1];
#pragma unroll
    for (int dd = 0; dd < 10; ++dd) {
      l0 = fmaf(rr[dd], wf[dd * 2 + 0], l0);
      l1 = fmaf(rr[dd], wf[dd * 2 + 1], l1);
    }
    float m = fmaxf(l0, l1);
    float e0 = expf(l0 - m), e1 = expf(l1 - m);
    float inv = 1.0f / (e0 + e1);
    out[(b * 2 + dir) * 2 + 0] = e0 * inv;
    out[(b * 2 + dir) * 2 + 1] = e1 * inv;
  }
}

// ---------------------------------------------------------------------------
extern "C" void kernel_launch(void* const* d_in, const int* in_sizes, int n_in,
                              void* d_out, int out_size, void* d_ws, size_t ws_size,
                              hipStream_t stream) {
  const int*   inputs = (const int*)d_in[0];
  const float* emb = (const float*)d_in[1];
  const float* w1 = (const float*)d_in[2];
  const float* b1 = (const float*)d_in[3];
  const float* w2 = (const float*)d_in[4];
  const float* b2 = (const float*)d_in[5];
  const float* w3 = (const float*)d_in[6];
  const float* b3 = (const float*)d_in[7];
  const float* wq = (const float*)d_in[8];
  const float* bq = (const float*)d_in[9];
  const float* wk = (const float*)d_in[10];
  const float* bk = (const float*)d_in[11];
  const float* wv = (const float*)d_in[12];
  const float* bv = (const float*)d_in[13];
  const float* wo = (const float*)d_in[14];
  const float* bo = (const float*)d_in[15];
  const float* wf = (const float*)d_in[16];
  const float* bf = (const float*)d_in[17];
  float* out = (float*)d_out;

  float* fbuf = (float*)d_ws;                 // 64*500 floats = 128 KB
  float* convout = (float*)d_ws + 32768;      // 64*10*16384 floats = 40 MB

  hipLaunchKernelGGL(conv_fused_kernel, dim3(NBS * NCHUNK), dim3(256), 0, stream,
                     inputs, emb, w1, b1, w2, b2, w3, b3, convout);
  hipLaunchKernelGGL(topk_kernel, dim3(NBS * 10), dim3(256), 0, stream, convout, fbuf);
  hipLaunchKernelGGL(mha_kernel, dim3(NBS), dim3(256), 0, stream,
                     fbuf, wq, bq, wk, bk, wv, bv, wo, bo, wf, bf, out);
}

// Round 6
// 249.365 us; speedup vs baseline: 1.3313x; 1.3313x over previous
//
#include <hip/hip_runtime.h>
#include <hip/hip_bf16.h>

#define LSEQ   16384
#define BATCH  32
#define NBS    64              // B*2 sequences
#define CHUNK  448
#define NCHUNK 37              // ceil(16384/448)

// ---------------------------------------------------------------------------
// Fused 3-layer conv kernel (round-1/3/4 verified core) + per-chunk top-50
// candidates via in-wave register bitonic (no LDS churn, no syncs, no atomics).
// ---------------------------------------------------------------------------

__device__ __forceinline__ void mac10x10(float acc[10], const float x[10],
                                         const float* __restrict__ wr) {
#pragma unroll
  for (int wi = 0; wi < 10; ++wi) {
    float xv = x[wi];
#pragma unroll
    for (int w = 0; w < 10; ++w) {
      acc[w] = fmaf(xv, wr[wi - w + 10], acc[w]);   // kw = wi-w+10 in [1,19]
    }
  }
}

template <int NPAIRS, int LREL0>
__device__ __forceinline__ void conv_stage(const float* __restrict__ bufIn,
                                           float* __restrict__ bufOut,
                                           const float* __restrict__ W, float bias,
                                           int base, int tid) {
  if (tid < NPAIRS) {
    float acc0[10], acc1[10];
#pragma unroll
    for (int w = 0; w < 10; ++w) { acc0[w] = bias; acc1[w] = bias; }
    float x[10];
    const float* src;

    // cp = 0 : input row rr = 2*tid (+0), contributes only to row0 (kh=0)
    src = bufIn + tid;
#pragma unroll
    for (int wi = 0; wi < 10; ++wi) x[wi] = src[wi * 512];
    mac10x10(acc0, x, W);

    for (int cp = 1; cp < 22; ++cp) {
      src = bufIn + (cp & 1) * 256 + tid + (cp >> 1);
#pragma unroll
      for (int wi = 0; wi < 10; ++wi) x[wi] = src[wi * 512];
      mac10x10(acc0, x, W + cp * 22);        // kh = cp   for row0
      mac10x10(acc1, x, W + (cp - 1) * 22);  // kh = cp-1 for row1
    }

    // cp = 22 : contributes only to row1 (kh=21)
    src = bufIn + tid + 11;
#pragma unroll
    for (int wi = 0; wi < 10; ++wi) x[wi] = src[wi * 512];
    mac10x10(acc1, x, W + 21 * 22);

    // relu + zero-mask rows outside [0, L)
    int g0 = base + 2 * tid + LREL0;
    bool v0 = (g0 >= 0) && (g0 < LSEQ);
    bool v1 = (g0 + 1 >= 0) && (g0 + 1 < LSEQ);
#pragma unroll
    for (int w = 0; w < 10; ++w) {
      bufOut[w * 512 + tid]       = v0 ? fmaxf(acc0[w], 0.0f) : 0.0f;
      bufOut[w * 512 + 256 + tid] = v1 ? fmaxf(acc1[w], 0.0f) : 0.0f;
    }
  }
}

// Merge two DESCENDING sorted 64-lists (one elem/lane) keeping the top-64 of
// the union, result descending. Bitonic-halver: max(A, reverse(B)) holds the
// 64 largest and is bitonic; 6-step clean sorts it.
__device__ __forceinline__ float bitonic_merge64(float a, float b, int lane) {
  float rb = __shfl(b, 63 - lane, 64);
  float m = fmaxf(a, rb);
#pragma unroll
  for (int j = 32; j > 0; j >>= 1) {
    float o = __shfl_xor(m, j, 64);
    m = ((lane & j) == 0) ? fmaxf(m, o) : fminf(m, o);
  }
  return m;
}

__global__ __launch_bounds__(256) void conv_fused_kernel(
    const int* __restrict__ inputs, const float* __restrict__ emb,
    const float* __restrict__ w1, const float* __restrict__ b1,
    const float* __restrict__ w2, const float* __restrict__ b2,
    const float* __restrict__ w3, const float* __restrict__ b3,
    float* __restrict__ cand /* [NBS*10][NCHUNK][50] */) {
  __shared__ float bufA[10 * 512];
  __shared__ float bufB[10 * 512];

  int blk = blockIdx.x;
  int bs = blk / NCHUNK;
  int chunk = blk - bs * NCHUNK;
  int base = chunk * CHUNK;
  int tid = threadIdx.x;

  // ---- gather: emb rows [base-30, base+482)  (512 rows = 256 pairs) ----
  const int* tokp = inputs + bs * LSEQ;
#pragma unroll
  for (int j = 0; j < 2; ++j) {
    int rr = 2 * tid + j;
    int glob = base - 30 + rr;
    float v[10];
    if (glob >= 0 && glob < LSEQ) {
      int tok = tokp[glob];
      const float2* er = reinterpret_cast<const float2*>(emb + tok * 10);
#pragma unroll
      for (int k = 0; k < 5; ++k) { float2 t = er[k]; v[2 * k] = t.x; v[2 * k + 1] = t.y; }
    } else {
#pragma unroll
      for (int wi = 0; wi < 10; ++wi) v[wi] = 0.0f;
    }
#pragma unroll
    for (int wi = 0; wi < 10; ++wi) bufA[wi * 512 + j * 256 + tid] = v[wi];
  }
  __syncthreads();

  // conv1: rows [-20, 470) relative to base   (245 pairs)
  conv_stage<245, -20>(bufA, bufB, w1, b1[0], base, tid);
  __syncthreads();
  // conv2: rows [-10, 460)                    (235 pairs)
  conv_stage<235, -10>(bufB, bufA, w2, b2[0], base, tid);
  __syncthreads();
  // conv3: rows [0, 448)                      (224 pairs)
  conv_stage<224, 0>(bufA, bufB, w3, b3[0], base, tid);
  __syncthreads();

  // ---- per-chunk exact top-50 per channel, in-wave (no LDS writes/syncs) --
  // Wave wv handles channels {wv, wv+4, wv+8}. Each lane loads 8 of the 512
  // tile slots (stride-1 across lanes -> conflict-free ds_read). Slot
  // validity: (idx & 255) < 224 (parity-interleaved layout, 448 real rows;
  // out-of-range rows are exact 0.0 which cannot perturb top-50 values).
  {
    int wv = tid >> 6, lane = tid & 63;
    for (int ci = 0; ci < 3; ++ci) {
      int ch = wv + ci * 4;
      if (ch >= 10) break;                   // wave-uniform branch
      float x[8];
#pragma unroll
      for (int s = 0; s < 8; ++s) {
        int idx = s * 64 + lane;
        float v = bufB[ch * 512 + idx];
        x[s] = ((idx & 255) < 224) ? v : -1.0f;   // pad < any relu output
      }
      // sort each 64-wide segment descending across lanes (bitonic, shfl_xor)
#pragma unroll
      for (int s = 0; s < 8; ++s) {
        float v = x[s];
#pragma unroll
        for (int k = 2; k <= 64; k <<= 1) {
#pragma unroll
          for (int j = k >> 1; j > 0; j >>= 1) {
            float o = __shfl_xor(v, j, 64);
            bool keepmax = (((lane & k) == 0) == ((lane & j) == 0));
            v = keepmax ? fmaxf(v, o) : fminf(v, o);
          }
        }
        x[s] = v;
      }
      // merge tree: 8 -> 4 -> 2 -> 1 sorted top-64 (exact top-64 of 512)
      float y0 = bitonic_merge64(x[0], x[1], lane);
      float y1 = bitonic_merge64(x[2], x[3], lane);
      float y2 = bitonic_merge64(x[4], x[5], lane);
      float y3 = bitonic_merge64(x[6], x[7], lane);
      float z0 = bitonic_merge64(y0, y1, lane);
      float z1 = bitonic_merge64(y2, y3, lane);
      float t  = bitonic_merge64(z0, z1, lane);
      if (lane < 50)
        cand[((bs * 10 + ch) * NCHUNK + chunk) * 50 + lane] = t;
    }
  }
}

// ---------------------------------------------------------------------------
// Merge: per (bs, d), top-50 (sorted desc) of 37*50=1850 chunk candidates.
// (Verbatim from the round-2 passing run.)
// ---------------------------------------------------------------------------
__global__ __launch_bounds__(256) void merge_topk_kernel(
    const float* __restrict__ cand, float* __restrict__ fbuf) {
  __shared__ float ml[2048];
  int blk = blockIdx.x;            // bs*10 + d
  int tid = threadIdx.x;
  const float* src = cand + blk * (NCHUNK * 50);
  for (int i = tid; i < 2048; i += 256) ml[i] = (i < NCHUNK * 50) ? src[i] : -1.0f;
  for (int k = 2; k <= 2048; k <<= 1) {
    for (int j = k >> 1; j > 0; j >>= 1) {
      __syncthreads();
      for (int e = tid; e < 1024; e += 256) {
        int lo = ((e & ~(j - 1)) << 1) | (e & (j - 1));
        int hi = lo | j;
        float a = ml[lo], b = ml[hi];
        bool desc = ((lo & k) == 0);
        if ((a < b) == desc) { ml[lo] = b; ml[hi] = a; }
      }
    }
  }
  __syncthreads();
  if (tid < 50) {
    int bs = blk / 10, d = blk - bs * 10;
    fbuf[bs * 500 + tid * 10 + d] = ml[tid];
  }
}

// ---------------------------------------------------------------------------
// Per-(batch, direction) MHA + sum over queries + final dense + softmax.
// ---------------------------------------------------------------------------
__global__ __launch_bounds__(256) void mha_kernel(
    const float* __restrict__ fbuf,
    const float* __restrict__ wq, const float* __restrict__ bq,
    const float* __restrict__ wk, const float* __restrict__ bk,
    const float* __restrict__ wv, const float* __restrict__ bv,
    const float* __restrict__ wo, const float* __restrict__ bo,
    const float* __restrict__ wf, const float* __restrict__ bf,
    float* __restrict__ out) {
  __shared__ float f[2][50][10];
  __shared__ float Qm[50][2][10];
  __shared__ float Km[50][2][10];
  __shared__ float Vm[50][2][10];
  __shared__ float A2[2][50][50];
  __shared__ float Abar[2][50];
  __shared__ float OS[2][10];
  __shared__ float rr[10];

  int blk = blockIdx.x, b = blk >> 1, dir = blk & 1;
  int qs = dir, ks = dir ^ 1;
  int tid = threadIdx.x;

  for (int i = tid; i < 1000; i += 256) (&f[0][0][0])[i] = fbuf[b * 1000 + i];
  __syncthreads();

  // projections: Q from f[qs], K/V from f[ks]
  for (int i = tid; i < 1000; i += 256) {
    int q = i / 20, rem = i - q * 20;
    int h = rem / 10, e = rem - h * 10;
    const float* fq = f[qs][q];
    const float* fk = f[ks][q];
    float aq = bq[h * 10 + e], ak = bk[h * 10 + e], av = bv[h * 10 + e];
#pragma unroll
    for (int dd = 0; dd < 10; ++dd) {
      int wIdx = dd * 20 + h * 10 + e;
      aq = fmaf(fq[dd], wq[wIdx], aq);
      ak = fmaf(fk[dd], wk[wIdx], ak);
      av = fmaf(fk[dd], wv[wIdx], av);
    }
    Qm[q][h][e] = aq; Km[q][h][e] = ak; Vm[q][h][e] = av;
  }
  __syncthreads();

  // softmax rows (h, q)
  for (int row = tid; row < 100; row += 256) {
    int h = row / 50, q = row - h * 50;
    const float* Qr = Qm[q][h];
    float lg[50], m = -1e30f;
#pragma unroll
    for (int s = 0; s < 50; ++s) {
      const float* Kr = Km[s][h];
      float t = 0.0f;
#pragma unroll
      for (int e = 0; e < 10; ++e) t = fmaf(Qr[e], Kr[e], t);
      t *= 0.31622776601683794f;   // 1/sqrt(10)
      lg[s] = t; m = fmaxf(m, t);
    }
    float sum = 0.0f;
#pragma unroll
    for (int s = 0; s < 50; ++s) { float p = __expf(lg[s] - m); lg[s] = p; sum += p; }
    float inv = 1.0f / sum;
#pragma unroll
    for (int s = 0; s < 50; ++s) A2[h][q][s] = lg[s] * inv;
  }
  __syncthreads();

  // Abar[h][s] = sum_q A[h][q][s]
  for (int i = tid; i < 100; i += 256) {
    int h = i / 50, s = i - h * 50;
    float t = 0.0f;
#pragma unroll
    for (int q = 0; q < 50; ++q) t += A2[h][q][s];
    Abar[h][s] = t;
  }
  __syncthreads();
  if (tid < 20) {
    int h = tid / 10, e = tid - h * 10;
    float t = 0.0f;
#pragma unroll
    for (int s = 0; s < 50; ++s) t += Abar[h][s] * Vm[s][h][e];
    OS[h][e] = t;
  }
  __syncthreads();
  if (tid < 10) {
    int dc = tid;
    float t = 50.0f * bo[dc];
#pragma unroll
    for (int h = 0; h < 2; ++h)
#pragma unroll
      for (int e = 0; e < 10; ++e) t = fmaf(OS[h][e], wo[h * 100 + e * 10 + dc], t);
    rr[dc] = t;
  }
  __syncthreads();
  if (tid == 0) {
    float l0 = bf[0], l1 = bf[1];
#pragma unroll
    for (int dd = 0; dd < 10; ++dd) {
      l0 = fmaf(rr[dd], wf[dd * 2 + 0], l0);
      l1 = fmaf(rr[dd], wf[dd * 2 + 1], l1);
    }
    float m = fmaxf(l0, l1);
    float e0 = expf(l0 - m), e1 = expf(l1 - m);
    float inv = 1.0f / (e0 + e1);
    out[(b * 2 + dir) * 2 + 0] = e0 * inv;
    out[(b * 2 + dir) * 2 + 1] = e1 * inv;
  }
}

// ---------------------------------------------------------------------------
extern "C" void kernel_launch(void* const* d_in, const int* in_sizes, int n_in,
                              void* d_out, int out_size, void* d_ws, size_t ws_size,
                              hipStream_t stream) {
  const int*   inputs = (const int*)d_in[0];
  const float* emb = (const float*)d_in[1];
  const float* w1 = (const float*)d_in[2];
  const float* b1 = (const float*)d_in[3];
  const float* w2 = (const float*)d_in[4];
  const float* b2 = (const float*)d_in[5];
  const float* w3 = (const float*)d_in[6];
  const float* b3 = (const float*)d_in[7];
  const float* wq = (const float*)d_in[8];
  const float* bq = (const float*)d_in[9];
  const float* wk = (const float*)d_in[10];
  const float* bk = (const float*)d_in[11];
  const float* wv = (const float*)d_in[12];
  const float* bv = (const float*)d_in[13];
  const float* wo = (const float*)d_in[14];
  const float* bo = (const float*)d_in[15];
  const float* wf = (const float*)d_in[16];
  const float* bf = (const float*)d_in[17];
  float* out = (float*)d_out;

  float* fbuf = (float*)d_ws;                 // 64*500 floats = 128 KB
  float* cand = (float*)d_ws + 32768;         // 64*10*37*50 floats = 4.74 MB

  hipLaunchKernelGGL(conv_fused_kernel, dim3(NBS * NCHUNK), dim3(256), 0, stream,
                     inputs, emb, w1, b1, w2, b2, w3, b3, cand);
  hipLaunchKernelGGL(merge_topk_kernel, dim3(NBS * 10), dim3(256), 0, stream, cand, fbuf);
  hipLaunchKernelGGL(mha_kernel, dim3(NBS), dim3(256), 0, stream,
                     fbuf, wq, bq, wk, bk, wv, bv, wo, bo, wf, bf, out);
}